// Round 1
// baseline (6970.913 us; speedup 1.0000x reference)
//
#include <hip/hip_runtime.h>
#include <math.h>

typedef unsigned short u16;
typedef __attribute__((ext_vector_type(8))) short short8;
typedef __attribute__((ext_vector_type(8))) u16 ushort8_t;
typedef __attribute__((ext_vector_type(4))) u16 ushort4_t;
typedef __attribute__((ext_vector_type(4))) float f32x4;

#define BB 2
#define TT 1024
#define EE 768
#define HH 12
#define HSZ 64
#define LL 12
#define FF 3072
#define VV 50257
#define MM 2048   // B*T rows

__device__ __forceinline__ float bf2f(u16 u) {
    union { unsigned int i; float f; } c;
    c.i = ((unsigned int)u) << 16;
    return c.f;
}
__device__ __forceinline__ u16 f2bf(float f) {
    unsigned int u = __float_as_uint(f);
    unsigned int r = (u + 0x7FFFu + ((u >> 16) & 1u)) >> 16;
    return (u16)r;
}

// ---------------------------------------------------------------- embedding
__global__ void embed_kernel(const int* __restrict__ x, const float* __restrict__ tok,
                             const float* __restrict__ pos, float* __restrict__ h,
                             u16* __restrict__ hb)
{
    int row = blockIdx.x;          // 0..2047 = b*1024+t
    int t = row & (TT - 1);
    int id = x[row];
    const float* tr = tok + (size_t)id * EE;
    const float* pr = pos + (size_t)t * EE;
    for (int i = threadIdx.x; i < EE; i += blockDim.x) {
        float v = tr[i] + pr[i];
        h[(size_t)row * EE + i] = v;
        hb[(size_t)row * EE + i] = f2bf(v);
    }
}

// ---------------------------------------------------------------- add + LN
// hout = LN(hin (+ add)) * w + b ; also emits bf16 copy. wave-per-row, 4 rows/block
__global__ __launch_bounds__(256)
void add_ln_kernel(const float* __restrict__ hin, const float* __restrict__ add,
                   const float* __restrict__ w, const float* __restrict__ bias,
                   float* __restrict__ hout, u16* __restrict__ hbout)
{
    int lane = threadIdx.x & 63, wv = threadIdx.x >> 6;
    int row = blockIdx.x * 4 + wv;
    const float* hp = hin + (size_t)row * EE;
    float x[12];
    float s = 0.f;
#pragma unroll
    for (int c = 0; c < 3; ++c) {
        float4 hv = *reinterpret_cast<const float4*>(hp + c * 256 + lane * 4);
        if (add) {
            float4 av = *reinterpret_cast<const float4*>(add + (size_t)row * EE + c * 256 + lane * 4);
            hv.x += av.x; hv.y += av.y; hv.z += av.z; hv.w += av.w;
        }
        x[c * 4 + 0] = hv.x; x[c * 4 + 1] = hv.y; x[c * 4 + 2] = hv.z; x[c * 4 + 3] = hv.w;
        s += hv.x + hv.y + hv.z + hv.w;
    }
#pragma unroll
    for (int o = 32; o > 0; o >>= 1) s += __shfl_xor(s, o);
    float mu = s * (1.0f / EE);
    float vs = 0.f;
#pragma unroll
    for (int i = 0; i < 12; ++i) { float d = x[i] - mu; vs += d * d; }
#pragma unroll
    for (int o = 32; o > 0; o >>= 1) vs += __shfl_xor(vs, o);
    float inv = 1.0f / sqrtf(vs * (1.0f / EE) + 1e-5f);
#pragma unroll
    for (int c = 0; c < 3; ++c) {
        int col = c * 256 + lane * 4;
        float4 wv4 = *reinterpret_cast<const float4*>(w + col);
        float4 bv4 = *reinterpret_cast<const float4*>(bias + col);
        float4 o;
        o.x = (x[c * 4 + 0] - mu) * inv * wv4.x + bv4.x;
        o.y = (x[c * 4 + 1] - mu) * inv * wv4.y + bv4.y;
        o.z = (x[c * 4 + 2] - mu) * inv * wv4.z + bv4.z;
        o.w = (x[c * 4 + 3] - mu) * inv * wv4.w + bv4.w;
        *reinterpret_cast<float4*>(hout + (size_t)row * EE + col) = o;
        ushort4_t ob;
        ob[0] = f2bf(o.x); ob[1] = f2bf(o.y); ob[2] = f2bf(o.z); ob[3] = f2bf(o.w);
        *reinterpret_cast<ushort4_t*>(hbout + (size_t)row * EE + col) = ob;
    }
}

// ---------------------------------------------------------------- GEMM
// C[M,N] = A[M,K](bf16) * W[N,K](fp32, row-major over K)^T  (+bias, +act)
#define BM 128
#define BN 128
#define BK 64
#define LDP 72   // bf16 elems per LDS row (64 + 16B pad)

enum { EPI_BF16 = 0, EPI_GELU_BF16 = 1, EPI_BIAS_F32 = 2, EPI_F32 = 3 };

template<int EPI, bool NGUARD>
__global__ __launch_bounds__(256, 2)
void gemm_kernel(const u16* __restrict__ A, const float* __restrict__ Bw,
                 const float* __restrict__ bias, void* __restrict__ Cout,
                 int Ndim, int Kdim)
{
    __shared__ u16 As[BM][LDP];
    __shared__ u16 Bs[BN][LDP];
    const int tid = threadIdx.x;
    const int lane = tid & 63;
    const int wid = tid >> 6;
    const int wm = wid >> 1, wn = wid & 1;
    const int rowBase = blockIdx.y * BM;
    const int colBase = blockIdx.x * BN;

    f32x4 acc[4][4] = {};

    for (int k0 = 0; k0 < Kdim; k0 += BK) {
        // stage A: 128x64 bf16
        {
            int r = tid >> 3;
            int c = (tid & 7) * 8;
#pragma unroll
            for (int it = 0; it < 4; ++it) {
                int row = it * 32 + r;
                ushort8_t v = *reinterpret_cast<const ushort8_t*>(
                    A + (size_t)(rowBase + row) * Kdim + k0 + c);
                *reinterpret_cast<ushort8_t*>(&As[row][c]) = v;
            }
        }
        // stage B: 128x64 fp32 -> bf16
        {
            int r = tid >> 4;
            int c = (tid & 15) * 4;
#pragma unroll
            for (int it = 0; it < 8; ++it) {
                int row = it * 16 + r;
                float4 v;
                if (!NGUARD || (colBase + row) < Ndim)
                    v = *reinterpret_cast<const float4*>(
                        Bw + (size_t)(colBase + row) * Kdim + k0 + c);
                else
                    v = make_float4(0.f, 0.f, 0.f, 0.f);
                ushort4_t o;
                o[0] = f2bf(v.x); o[1] = f2bf(v.y); o[2] = f2bf(v.z); o[3] = f2bf(v.w);
                *reinterpret_cast<ushort4_t*>(&Bs[row][c]) = o;
            }
        }
        __syncthreads();
#pragma unroll
        for (int kk = 0; kk < BK; kk += 32) {
            short8 af[4], bfr[4];
            int kcol = kk + (lane >> 4) * 8;
#pragma unroll
            for (int mi = 0; mi < 4; ++mi)
                af[mi] = *reinterpret_cast<const short8*>(&As[wm * 64 + mi * 16 + (lane & 15)][kcol]);
#pragma unroll
            for (int ni = 0; ni < 4; ++ni)
                bfr[ni] = *reinterpret_cast<const short8*>(&Bs[wn * 64 + ni * 16 + (lane & 15)][kcol]);
#pragma unroll
            for (int mi = 0; mi < 4; ++mi)
#pragma unroll
                for (int ni = 0; ni < 4; ++ni)
                    acc[mi][ni] = __builtin_amdgcn_mfma_f32_16x16x32_bf16(
                        af[mi], bfr[ni], acc[mi][ni], 0, 0, 0);
        }
        __syncthreads();
    }

    // epilogue: D row = (lane>>4)*4 + reg, col = lane&15  [m89-verified layout]
#pragma unroll
    for (int mi = 0; mi < 4; ++mi) {
#pragma unroll
        for (int ni = 0; ni < 4; ++ni) {
#pragma unroll
            for (int r = 0; r < 4; ++r) {
                int row = rowBase + wm * 64 + mi * 16 + (lane >> 4) * 4 + r;
                int col = colBase + wn * 64 + ni * 16 + (lane & 15);
                if (NGUARD && col >= Ndim) continue;
                float v = acc[mi][ni][r];
                if (EPI == EPI_GELU_BF16) { v += bias[col]; v = 0.5f * v * (1.0f + erff(v * 0.70710678f)); }
                if (EPI == EPI_BIAS_F32)  { v += bias[col]; }
                size_t idx = (size_t)row * Ndim + col;
                if (EPI == EPI_BF16 || EPI == EPI_GELU_BF16)
                    ((u16*)Cout)[idx] = f2bf(v);
                else
                    ((float*)Cout)[idx] = v;
            }
        }
    }
}

// ---------------------------------------------------------------- attention
// Reference (transposed roles): out[b,s,h,:] = sum_{t<=s} softmax_t(k[b,s]·q[b,t]*scale) * v[b,t]
// wave per output row s; scores staged in LDS (2-pass softmax).
__global__ __launch_bounds__(256)
void attn_kernel(const u16* __restrict__ q, const u16* __restrict__ k,
                 const u16* __restrict__ v, float* __restrict__ aout)
{
    __shared__ float p_lds[4][TT];
    int lane = threadIdx.x & 63, wv = threadIdx.x >> 6;
    int s = blockIdx.x * 4 + wv;
    int bh = blockIdx.y;
    int b = bh / HH, h = bh % HH;
    const float scale = 0.036084392f;  // 1/sqrt(768)
    size_t base = ((size_t)b * TT) * EE + h * HSZ;

    // k[s] row -> registers (broadcast loads, all lanes same addr)
    const ushort8_t* kp = reinterpret_cast<const ushort8_t*>(k + base + (size_t)s * EE);
    float kf[64];
#pragma unroll
    for (int c = 0; c < 8; ++c) {
        ushort8_t kv = kp[c];
#pragma unroll
        for (int e = 0; e < 8; ++e) kf[c * 8 + e] = bf2f(kv[e]);
    }

    // phase 1: scores -> LDS, track max
    float mx = -INFINITY;
    int jmax = s >> 6;
    for (int j = 0; j <= jmax; ++j) {
        int t = j * 64 + lane;
        float sc = -INFINITY;
        if (t <= s) {
            const ushort8_t* qp = reinterpret_cast<const ushort8_t*>(q + base + (size_t)t * EE);
            float acc = 0.f;
#pragma unroll
            for (int c = 0; c < 8; ++c) {
                ushort8_t qv = qp[c];
#pragma unroll
                for (int e = 0; e < 8; ++e) acc += kf[c * 8 + e] * bf2f(qv[e]);
            }
            sc = acc * scale;
        }
        p_lds[wv][j * 64 + lane] = sc;
        mx = fmaxf(mx, sc);
    }
#pragma unroll
    for (int o = 32; o > 0; o >>= 1) mx = fmaxf(mx, __shfl_xor(mx, o));

    // exp + sum
    float sum = 0.f;
    for (int t = lane; t <= s; t += 64) {
        float val = __expf(p_lds[wv][t] - mx);
        sum += val;
        p_lds[wv][t] = val;
    }
#pragma unroll
    for (int o = 32; o > 0; o >>= 1) sum += __shfl_xor(sum, o);
    float inv = 1.0f / sum;

    __syncthreads();  // paranoia only; p_lds is wave-private

    // phase 2: O[d=lane] = sum_t p[t] * v[t,d]
    float O = 0.f;
    int nfull = (s + 1) & ~3;
    int t = 0;
    for (; t < nfull; t += 4) {
        float4 pv = *reinterpret_cast<const float4*>(&p_lds[wv][t]);
        O += pv.x * bf2f(v[base + (size_t)(t + 0) * EE + lane]);
        O += pv.y * bf2f(v[base + (size_t)(t + 1) * EE + lane]);
        O += pv.z * bf2f(v[base + (size_t)(t + 2) * EE + lane]);
        O += pv.w * bf2f(v[base + (size_t)(t + 3) * EE + lane]);
    }
    for (; t <= s; ++t) O += p_lds[wv][t] * bf2f(v[base + (size_t)t * EE + lane]);

    aout[base + (size_t)s * EE + lane] = O * inv;
}

// ---------------------------------------------------------------- driver
extern "C" void kernel_launch(void* const* d_in, const int* in_sizes, int n_in,
                              void* d_out, int out_size, void* d_ws, size_t ws_size,
                              hipStream_t stream)
{
    const int*   x    = (const int*)d_in[0];
    const float* tok  = (const float*)d_in[1];
    const float* pos  = (const float*)d_in[2];
    const float* qW   = (const float*)d_in[3];
    const float* kW   = (const float*)d_in[4];
    const float* vW   = (const float*)d_in[5];
    const float* ln1w = (const float*)d_in[6];
    const float* ln1b = (const float*)d_in[7];
    const float* fc1w = (const float*)d_in[8];
    const float* fc1b = (const float*)d_in[9];
    const float* fc2w = (const float*)d_in[10];
    const float* fc2b = (const float*)d_in[11];
    const float* ln2w = (const float*)d_in[12];
    const float* ln2b = (const float*)d_in[13];
    const float* lnfw = (const float*)d_in[14];
    const float* lnfb = (const float*)d_in[15];
    const float* lmw  = (const float*)d_in[16];
    float* out = (float*)d_out;

    char* ws = (char*)d_ws;
    float* h   = (float*)ws;  ws += (size_t)MM * EE * 4;
    float* tmp = (float*)ws;  ws += (size_t)MM * EE * 4;
    u16* hb = (u16*)ws;       ws += (size_t)MM * EE * 2;
    u16* qb = (u16*)ws;       ws += (size_t)MM * EE * 2;
    u16* kb = (u16*)ws;       ws += (size_t)MM * EE * 2;
    u16* vb = (u16*)ws;       ws += (size_t)MM * EE * 2;
    u16* mb = (u16*)ws;       ws += (size_t)MM * FF * 2;

    dim3 blk(256);
    dim3 gE(EE / BN, MM / BM);      // N=768
    dim3 gF(FF / BN, MM / BM);      // N=3072
    dim3 gV((VV + BN - 1) / BN, MM / BM);
    dim3 gAttn(TT / 4, BB * HH);

    embed_kernel<<<MM, blk, 0, stream>>>(x, tok, pos, h, hb);

    for (int l = 0; l < LL; ++l) {
        const float* qWl = qW + (size_t)l * EE * EE;
        const float* kWl = kW + (size_t)l * EE * EE;
        const float* vWl = vW + (size_t)l * EE * EE;
        gemm_kernel<EPI_BF16, false><<<gE, blk, 0, stream>>>(hb, qWl, nullptr, qb, EE, EE);
        gemm_kernel<EPI_BF16, false><<<gE, blk, 0, stream>>>(hb, kWl, nullptr, kb, EE, EE);
        gemm_kernel<EPI_BF16, false><<<gE, blk, 0, stream>>>(hb, vWl, nullptr, vb, EE, EE);
        attn_kernel<<<gAttn, blk, 0, stream>>>(qb, kb, vb, tmp);
        add_ln_kernel<<<MM / 4, blk, 0, stream>>>(h, tmp, ln1w + l * EE, ln1b + l * EE, h, hb);
        gemm_kernel<EPI_GELU_BF16, false><<<gF, blk, 0, stream>>>(
            hb, fc1w + (size_t)l * FF * EE, fc1b + (size_t)l * FF, mb, FF, EE);
        gemm_kernel<EPI_BIAS_F32, false><<<gE, blk, 0, stream>>>(
            mb, fc2w + (size_t)l * EE * FF, fc2b + (size_t)l * EE, tmp, EE, FF);
        add_ln_kernel<<<MM / 4, blk, 0, stream>>>(h, tmp, ln2w + l * EE, ln2b + l * EE, h, hb);
    }
    add_ln_kernel<<<MM / 4, blk, 0, stream>>>(h, nullptr, lnfw, lnfb, h, hb);
    gemm_kernel<EPI_F32, true><<<gV, blk, 0, stream>>>(hb, lmw, nullptr, out, VV, EE);
}